// Round 1
// baseline (271.340 us; speedup 1.0000x reference)
//
#include <hip/hip_runtime.h>
#include <math.h>

#define BB 8
#define NN 2048
#define LL 2048
#define QQ 512
#define DD 512

// -------- Kernel A: per-(b,h,l) top-3 over q=512, softmax, pack to ws -----
// Block: 256 threads = 4 waves. wave g handles n-chunk [g*128, g*128+128),
// lane u handles l = blockIdx.x*64 + u. LDS merge of the 4 partial top-3s.
__global__ __launch_bounds__(256) void topk_kernel(
    const float* __restrict__ logits, float4* __restrict__ wpack) {
  const int u  = threadIdx.x & 63;   // l lane
  const int g  = threadIdx.x >> 6;   // n-chunk (wave id)
  const int lt = blockIdx.x;         // l tile (0..31)
  const int h  = blockIdx.y;         // head
  const int b  = blockIdx.z;         // batch
  const int l  = lt * 64 + u;

  const float* base =
      logits + ((size_t)(b * NN + h * QQ + g * 128) * LL) + l;

  float v0 = -INFINITY, v1 = -INFINITY, v2 = -INFINITY;
  int   i0 = 0, i1 = 0, i2 = 0;
#pragma unroll 4
  for (int n = 0; n < 128; ++n) {
    float v = base[(size_t)n * LL];
    int   i = g * 128 + n;
    bool gt0 = v > v0, gt1 = v > v1, gt2 = v > v2;
    float nv2 = gt1 ? v1 : (gt2 ? v : v2);
    int   ni2 = gt1 ? i1 : (gt2 ? i : i2);
    float nv1 = gt0 ? v0 : (gt1 ? v : v1);
    int   ni1 = gt0 ? i0 : (gt1 ? i : i1);
    v0 = gt0 ? v : v0;
    i0 = gt0 ? i : i0;
    v1 = nv1; i1 = ni1; v2 = nv2; i2 = ni2;
  }

  __shared__ float sv[4][64][3];
  __shared__ int   si[4][64][3];
  sv[g][u][0] = v0; sv[g][u][1] = v1; sv[g][u][2] = v2;
  si[g][u][0] = i0; si[g][u][1] = i1; si[g][u][2] = i2;
  __syncthreads();

  if (threadIdx.x < 64) {
    float m0 = sv[0][u][0], m1 = sv[0][u][1], m2 = sv[0][u][2];
    int   j0 = si[0][u][0], j1 = si[0][u][1], j2 = si[0][u][2];
#pragma unroll
    for (int gg = 1; gg < 4; ++gg) {
#pragma unroll
      for (int k = 0; k < 3; ++k) {
        float v = sv[gg][u][k];
        int   i = si[gg][u][k];
        bool gt0 = v > m0, gt1 = v > m1, gt2 = v > m2;
        float nv2 = gt1 ? m1 : (gt2 ? v : m2);
        int   ni2 = gt1 ? j1 : (gt2 ? i : j2);
        float nv1 = gt0 ? m0 : (gt1 ? v : m1);
        int   ni1 = gt0 ? j0 : (gt1 ? i : j1);
        m0 = gt0 ? v : m0;
        j0 = gt0 ? i : j0;
        m1 = nv1; j1 = ni1; m2 = nv2; j2 = ni2;
      }
    }
    // softmax over (m0 >= m1 >= m2)
    float e1 = __expf(m1 - m0), e2 = __expf(m2 - m0);
    float inv = 1.0f / (1.0f + e1 + e2);
    unsigned int pi = (unsigned int)j0 | ((unsigned int)j1 << 9) |
                      ((unsigned int)j2 << 18);
    float4 W = make_float4(inv, e1 * inv, e2 * inv, __uint_as_float(pi));
    wpack[(size_t)(b * 4 + h) * LL + l] = W;
  }
}

// -------- Kernel B: gather 12 emb rows, weighted sum, write (B,d,L) -------
// Block: 256 threads = 4 waves. lane u -> l (coalesced stores), wave dv ->
// 32-wide d sub-slice of this block's 128-wide d tile.
__global__ __launch_bounds__(256) void combine_kernel(
    const float4* __restrict__ wpack,
    const float* __restrict__ emb0, const float* __restrict__ emb1,
    const float* __restrict__ emb2, const float* __restrict__ emb3,
    float* __restrict__ out) {
  const int u  = threadIdx.x & 63;
  const int dv = threadIdx.x >> 6;   // 0..3
  const int lt = blockIdx.x;         // 0..31
  const int dt = blockIdx.y;         // 0..3 (128-wide d tile)
  const int b  = blockIdx.z;
  const int l  = lt * 64 + u;
  const int d0 = dt * 128 + dv * 32;

  const float* embs[4] = {emb0, emb1, emb2, emb3};
  float        w[12];
  const float* rows[12];
#pragma unroll
  for (int h = 0; h < 4; ++h) {
    float4 W = wpack[(size_t)(b * 4 + h) * LL + l];
    unsigned int pi = __float_as_uint(W.w);
    w[h * 3 + 0] = W.x;
    w[h * 3 + 1] = W.y;
    w[h * 3 + 2] = W.z;
    rows[h * 3 + 0] = embs[h] + (size_t)(pi & 511) * DD;
    rows[h * 3 + 1] = embs[h] + (size_t)((pi >> 9) & 511) * DD;
    rows[h * 3 + 2] = embs[h] + (size_t)((pi >> 18) & 511) * DD;
  }

  float* outb = out + (size_t)b * DD * LL + l;
#pragma unroll 2
  for (int j = 0; j < 8; ++j) {
    const int dd = d0 + j * 4;
    float a0 = 0.f, a1 = 0.f, a2 = 0.f, a3 = 0.f;
#pragma unroll
    for (int m = 0; m < 12; ++m) {
      const float4 e = *(const float4*)(rows[m] + dd);
      a0 += w[m] * e.x;
      a1 += w[m] * e.y;
      a2 += w[m] * e.z;
      a3 += w[m] * e.w;
    }
    outb[(size_t)(dd + 0) * LL] = a0;
    outb[(size_t)(dd + 1) * LL] = a1;
    outb[(size_t)(dd + 2) * LL] = a2;
    outb[(size_t)(dd + 3) * LL] = a3;
  }
}

extern "C" void kernel_launch(void* const* d_in, const int* in_sizes, int n_in,
                              void* d_out, int out_size, void* d_ws,
                              size_t ws_size, hipStream_t stream) {
  const float* logits = (const float*)d_in[0];
  const float* emb0   = (const float*)d_in[1];
  const float* emb1   = (const float*)d_in[2];
  const float* emb2   = (const float*)d_in[3];
  const float* emb3   = (const float*)d_in[4];
  float*       out    = (float*)d_out;
  float4*      wpack  = (float4*)d_ws;  // 8*4*2048 float4 = 1 MiB

  dim3 ga(LL / 64, 4, BB);  // (l-tiles, heads, batch) = 1024 blocks
  topk_kernel<<<ga, 256, 0, stream>>>(logits, wpack);

  dim3 gb(LL / 64, DD / 128, BB);  // (l-tiles, d-tiles, batch) = 1024 blocks
  combine_kernel<<<gb, 256, 0, stream>>>(wpack, emb0, emb1, emb2, emb3, out);
}

// Round 2
// 253.516 us; speedup vs baseline: 1.0703x; 1.0703x over previous
//
#include <hip/hip_runtime.h>
#include <math.h>

#define BB 8
#define NN 2048
#define LL 2048
#define QQ 512
#define DD 512

// -------- Kernel A: per-(b,h,l) top-3 over q=512, softmax, pack to ws -----
// Block 256 = 4 waves. Lane u loads float4 along L (l = lt*256 + u*4),
// keeping 4 independent top-3 trackers. Wave g covers n-chunk [g*128,+128).
// LDS merge of the 4 chunk-partials per l, softmax, pack float4 to wpack.
__global__ __launch_bounds__(256) void topk_kernel(
    const float* __restrict__ logits, float4* __restrict__ wpack) {
  const int u  = threadIdx.x & 63;
  const int g  = threadIdx.x >> 6;
  const int lt = blockIdx.x;   // 0..7 (256-wide l tile)
  const int h  = blockIdx.y;
  const int b  = blockIdx.z;
  const int l4 = lt * 256 + u * 4;

  const float* base =
      logits + ((size_t)(b * NN + h * QQ + g * 128) * LL) + l4;

  float v0[4], v1[4], v2[4];
  int   i0[4], i1[4], i2[4];
#pragma unroll
  for (int j = 0; j < 4; ++j) {
    v0[j] = v1[j] = v2[j] = -INFINITY;
    i0[j] = i1[j] = i2[j] = 0;
  }

#pragma unroll 8
  for (int n = 0; n < 128; ++n) {
    const float4 vv = *(const float4*)(base + (size_t)n * LL);
    const int i = g * 128 + n;
    const float ve[4] = {vv.x, vv.y, vv.z, vv.w};
#pragma unroll
    for (int j = 0; j < 4; ++j) {
      float v = ve[j];
      bool gt0 = v > v0[j], gt1 = v > v1[j], gt2 = v > v2[j];
      float nv2 = gt1 ? v1[j] : (gt2 ? v : v2[j]);
      int   ni2 = gt1 ? i1[j] : (gt2 ? i : i2[j]);
      float nv1 = gt0 ? v0[j] : (gt1 ? v : v1[j]);
      int   ni1 = gt0 ? i0[j] : (gt1 ? i : i1[j]);
      v0[j] = gt0 ? v : v0[j];
      i0[j] = gt0 ? i : i0[j];
      v1[j] = nv1; i1[j] = ni1; v2[j] = nv2; i2[j] = ni2;
    }
  }

  __shared__ float sv[4][256][3];
  __shared__ int   si[4][256][3];
#pragma unroll
  for (int j = 0; j < 4; ++j) {
    const int ll = u * 4 + j;
    sv[g][ll][0] = v0[j]; sv[g][ll][1] = v1[j]; sv[g][ll][2] = v2[j];
    si[g][ll][0] = i0[j]; si[g][ll][1] = i1[j]; si[g][ll][2] = i2[j];
  }
  __syncthreads();

  const int t = threadIdx.x;  // merge: one thread per l
  float m0 = sv[0][t][0], m1 = sv[0][t][1], m2 = sv[0][t][2];
  int   j0 = si[0][t][0], j1 = si[0][t][1], j2 = si[0][t][2];
#pragma unroll
  for (int gg = 1; gg < 4; ++gg) {
#pragma unroll
    for (int k = 0; k < 3; ++k) {
      float v = sv[gg][t][k];
      int   i = si[gg][t][k];
      bool gt0 = v > m0, gt1 = v > m1, gt2 = v > m2;
      float nv2 = gt1 ? m1 : (gt2 ? v : m2);
      int   ni2 = gt1 ? j1 : (gt2 ? i : j2);
      float nv1 = gt0 ? m0 : (gt1 ? v : m1);
      int   ni1 = gt0 ? j0 : (gt1 ? i : j1);
      m0 = gt0 ? v : m0;
      j0 = gt0 ? i : j0;
      m1 = nv1; j1 = ni1; m2 = nv2; j2 = ni2;
    }
  }
  float e1 = __expf(m1 - m0), e2 = __expf(m2 - m0);
  float inv = 1.0f / (1.0f + e1 + e2);
  unsigned int pi = (unsigned int)j0 | ((unsigned int)j1 << 9) |
                    ((unsigned int)j2 << 18);
  float4 W = make_float4(inv, e1 * inv, e2 * inv, __uint_as_float(pi));
  wpack[(size_t)(b * 4 + h) * LL + lt * 256 + t] = W;
}

// -------- Kernel B: coalesced gather + LDS transpose + coalesced store ----
// Block 256 = 4 waves, handles 16 l's × all 512 d. Phase 1: wave w owns
// l's w*4..w*4+3; all 64 lanes read the SAME emb row contiguously
// (float4/lane, 2 passes of 256 floats) -> weighted sum -> LDS tile.
// Phase 2: transposed read, float4-over-l stores (64B-line utilization).
__global__ __launch_bounds__(256) void combine_kernel(
    const float4* __restrict__ wpack,
    const float* __restrict__ emb0, const float* __restrict__ emb1,
    const float* __restrict__ emb2, const float* __restrict__ emb3,
    float* __restrict__ out) {
  const int u    = threadIdx.x & 63;
  const int w    = threadIdx.x >> 6;
  const int lblk = blockIdx.x * 16;  // 128 l-tiles
  const int b    = blockIdx.y;

  __shared__ float tile[16][516];  // stride 516: 2-way bank alias only (free)

  const float* embs[4] = {emb0, emb1, emb2, emb3};

#pragma unroll
  for (int il = 0; il < 4; ++il) {
    const int l = lblk + w * 4 + il;
    float wt[12];
    const float* rows[12];
#pragma unroll
    for (int h = 0; h < 4; ++h) {
      float4 W = wpack[(size_t)(b * 4 + h) * LL + l];  // broadcast load
      unsigned int pi = __float_as_uint(W.w);
      wt[h * 3 + 0] = W.x;
      wt[h * 3 + 1] = W.y;
      wt[h * 3 + 2] = W.z;
      rows[h * 3 + 0] = embs[h] + (size_t)(pi & 511) * DD;
      rows[h * 3 + 1] = embs[h] + (size_t)((pi >> 9) & 511) * DD;
      rows[h * 3 + 2] = embs[h] + (size_t)((pi >> 18) & 511) * DD;
    }
#pragma unroll
    for (int p = 0; p < 2; ++p) {
      const int d = p * 256 + u * 4;
      float a0 = 0.f, a1 = 0.f, a2 = 0.f, a3 = 0.f;
#pragma unroll
      for (int m = 0; m < 12; ++m) {
        const float4 e = *(const float4*)(rows[m] + d);  // coalesced 1KB/inst
        a0 += wt[m] * e.x;
        a1 += wt[m] * e.y;
        a2 += wt[m] * e.z;
        a3 += wt[m] * e.w;
      }
      float4 a = make_float4(a0, a1, a2, a3);
      *(float4*)&tile[w * 4 + il][d] = a;
    }
  }
  __syncthreads();

  // Phase 2: tid -> (l0 = (tid&3)*4, dof = tid>>2); float4 store over l.
  const int l0  = (threadIdx.x & 3) * 4;
  const int dof = threadIdx.x >> 2;  // 0..63
  float* outb = out + (size_t)b * DD * LL + lblk + l0;
#pragma unroll
  for (int dd = 0; dd < 512; dd += 64) {
    const int d = dd + dof;
    float4 r;
    r.x = tile[l0 + 0][d];
    r.y = tile[l0 + 1][d];
    r.z = tile[l0 + 2][d];
    r.w = tile[l0 + 3][d];
    *(float4*)(outb + (size_t)d * LL) = r;
  }
}

extern "C" void kernel_launch(void* const* d_in, const int* in_sizes, int n_in,
                              void* d_out, int out_size, void* d_ws,
                              size_t ws_size, hipStream_t stream) {
  const float* logits = (const float*)d_in[0];
  const float* emb0   = (const float*)d_in[1];
  const float* emb1   = (const float*)d_in[2];
  const float* emb2   = (const float*)d_in[3];
  const float* emb3   = (const float*)d_in[4];
  float*       out    = (float*)d_out;
  float4*      wpack  = (float4*)d_ws;  // 8*4*2048 float4 = 1 MiB

  dim3 ga(LL / 256, 4, BB);  // 256 blocks: 1/CU, 4 waves each
  topk_kernel<<<ga, 256, 0, stream>>>(logits, wpack);

  dim3 gb(LL / 16, BB);      // 1024 blocks
  combine_kernel<<<gb, 256, 0, stream>>>(wpack, emb0, emb1, emb2, emb3, out);
}

// Round 3
// 234.168 us; speedup vs baseline: 1.1587x; 1.0826x over previous
//
#include <hip/hip_runtime.h>
#include <math.h>

#define BB 8
#define NN 2048
#define LL 2048
#define QQ 512
#define DD 512

__device__ __forceinline__ void top3_insert(float v, int i, float& m0,
                                            float& m1, float& m2, int& j0,
                                            int& j1, int& j2) {
  bool gt0 = v > m0, gt1 = v > m1, gt2 = v > m2;
  float nv2 = gt1 ? m1 : (gt2 ? v : m2);
  int   ni2 = gt1 ? j1 : (gt2 ? i : j2);
  float nv1 = gt0 ? m0 : (gt1 ? v : m1);
  int   ni1 = gt0 ? j0 : (gt1 ? i : j1);
  m0 = gt0 ? v : m0;
  j0 = gt0 ? i : j0;
  m1 = nv1; j1 = ni1; m2 = nv2; j2 = ni2;
}

// -------- Kernel A1: partial top-3 over a 128-wide n-chunk ----------------
// Grid (8 lt, 4 h, 32 = b*4+ns), block 256 = 4 waves. Wave g scans 32 n's
// (chunk base ns*128 + g*32); lane u tracks 4 l's via float4 loads along L.
// Explicit 8-deep load batching keeps 8 loads in flight per wave.
// LDS-merge the 4 waves -> top-3 over 128 n's -> partial to d_ws.
__global__ __launch_bounds__(256) void topk_part_kernel(
    const float* __restrict__ logits, float4* __restrict__ part) {
  const int u  = threadIdx.x & 63;
  const int g  = threadIdx.x >> 6;
  const int lt = blockIdx.x;         // 0..7
  const int h  = blockIdx.y;         // 0..3
  const int b  = blockIdx.z >> 2;    // 0..7
  const int ns = blockIdx.z & 3;     // 0..3 (128-wide n chunk)
  const int l4 = lt * 256 + u * 4;
  const int n0 = ns * 128 + g * 32;

  const float* base = logits + ((size_t)(b * NN + h * QQ + n0) * LL) + l4;

  float v0[4], v1[4], v2[4];
  int   i0[4], i1[4], i2[4];
#pragma unroll
  for (int j = 0; j < 4; ++j) {
    v0[j] = v1[j] = v2[j] = -INFINITY;
    i0[j] = i1[j] = i2[j] = 0;
  }

  float4 buf[8];
  for (int t = 0; t < 4; ++t) {      // 4 batches of 8 n's
#pragma unroll
    for (int p = 0; p < 8; ++p)
      buf[p] = *(const float4*)(base + (size_t)(t * 8 + p) * LL);
#pragma unroll
    for (int p = 0; p < 8; ++p) {
      const int i = n0 + t * 8 + p;
      top3_insert(buf[p].x, i, v0[0], v1[0], v2[0], i0[0], i1[0], i2[0]);
      top3_insert(buf[p].y, i, v0[1], v1[1], v2[1], i0[1], i1[1], i2[1]);
      top3_insert(buf[p].z, i, v0[2], v1[2], v2[2], i0[2], i1[2], i2[2]);
      top3_insert(buf[p].w, i, v0[3], v1[3], v2[3], i0[3], i1[3], i2[3]);
    }
  }

  __shared__ float sv[4][256][3];
  __shared__ int   si[4][256][3];
#pragma unroll
  for (int j = 0; j < 4; ++j) {
    const int ll = u * 4 + j;
    sv[g][ll][0] = v0[j]; sv[g][ll][1] = v1[j]; sv[g][ll][2] = v2[j];
    si[g][ll][0] = i0[j]; si[g][ll][1] = i1[j]; si[g][ll][2] = i2[j];
  }
  __syncthreads();

  const int t = threadIdx.x;  // one thread per l
  float m0 = sv[0][t][0], m1 = sv[0][t][1], m2 = sv[0][t][2];
  int   j0 = si[0][t][0], j1 = si[0][t][1], j2 = si[0][t][2];
#pragma unroll
  for (int gg = 1; gg < 4; ++gg)
#pragma unroll
    for (int k = 0; k < 3; ++k)
      top3_insert(sv[gg][t][k], si[gg][t][k], m0, m1, m2, j0, j1, j2);

  unsigned int pi = (unsigned int)j0 | ((unsigned int)j1 << 9) |
                    ((unsigned int)j2 << 18);
  part[(size_t)(((b * 4 + h) * 4 + ns)) * LL + lt * 256 + t] =
      make_float4(m0, m1, m2, __uint_as_float(pi));
}

// -------- Kernel A2: merge 4 n-chunk partials, softmax, pack wpack --------
// 256 blocks x 256 threads; thread -> one (b,h,l). All loads/stores coalesced.
__global__ __launch_bounds__(256) void topk_merge_kernel(
    const float4* __restrict__ part, float4* __restrict__ wpack) {
  const int x   = blockIdx.x;        // (b*4+h)*8 + lt
  const int bh  = x >> 3;
  const int l   = (x & 7) * 256 + threadIdx.x;
  const size_t base = (size_t)bh * 4 * LL + l;

  float4 P = part[base];
  float m0 = P.x, m1 = P.y, m2 = P.z;
  unsigned int pi = __float_as_uint(P.w);
  int j0 = pi & 511, j1 = (pi >> 9) & 511, j2 = (pi >> 18) & 511;
#pragma unroll
  for (int ns = 1; ns < 4; ++ns) {
    float4 Q = part[base + (size_t)ns * LL];
    unsigned int qi = __float_as_uint(Q.w);
    top3_insert(Q.x, qi & 511, m0, m1, m2, j0, j1, j2);
    top3_insert(Q.y, (qi >> 9) & 511, m0, m1, m2, j0, j1, j2);
    top3_insert(Q.z, (qi >> 18) & 511, m0, m1, m2, j0, j1, j2);
  }
  float e1 = __expf(m1 - m0), e2 = __expf(m2 - m0);
  float inv = 1.0f / (1.0f + e1 + e2);
  unsigned int po = (unsigned int)j0 | ((unsigned int)j1 << 9) |
                    ((unsigned int)j2 << 18);
  wpack[(size_t)bh * LL + l] =
      make_float4(inv, e1 * inv, e2 * inv, __uint_as_float(po));
}

// -------- Kernel B: coalesced gather + LDS transpose + coalesced store ----
__global__ __launch_bounds__(256) void combine_kernel(
    const float4* __restrict__ wpack,
    const float* __restrict__ emb0, const float* __restrict__ emb1,
    const float* __restrict__ emb2, const float* __restrict__ emb3,
    float* __restrict__ out) {
  const int u    = threadIdx.x & 63;
  const int w    = threadIdx.x >> 6;
  const int lblk = blockIdx.x * 16;
  const int b    = blockIdx.y;

  __shared__ float tile[16][516];  // stride 516: 2-way bank alias only (free)

  const float* embs[4] = {emb0, emb1, emb2, emb3};

#pragma unroll
  for (int il = 0; il < 4; ++il) {
    const int l = lblk + w * 4 + il;
    float wt[12];
    const float* rows[12];
#pragma unroll
    for (int h = 0; h < 4; ++h) {
      float4 W = wpack[(size_t)(b * 4 + h) * LL + l];  // broadcast load
      unsigned int pi = __float_as_uint(W.w);
      wt[h * 3 + 0] = W.x;
      wt[h * 3 + 1] = W.y;
      wt[h * 3 + 2] = W.z;
      rows[h * 3 + 0] = embs[h] + (size_t)(pi & 511) * DD;
      rows[h * 3 + 1] = embs[h] + (size_t)((pi >> 9) & 511) * DD;
      rows[h * 3 + 2] = embs[h] + (size_t)((pi >> 18) & 511) * DD;
    }
#pragma unroll
    for (int p = 0; p < 2; ++p) {
      const int d = p * 256 + u * 4;
      float a0 = 0.f, a1 = 0.f, a2 = 0.f, a3 = 0.f;
#pragma unroll
      for (int m = 0; m < 12; ++m) {
        const float4 e = *(const float4*)(rows[m] + d);  // coalesced 1KB/inst
        a0 += wt[m] * e.x;
        a1 += wt[m] * e.y;
        a2 += wt[m] * e.z;
        a3 += wt[m] * e.w;
      }
      *(float4*)&tile[w * 4 + il][d] = make_float4(a0, a1, a2, a3);
    }
  }
  __syncthreads();

  const int l0  = (threadIdx.x & 3) * 4;
  const int dof = threadIdx.x >> 2;  // 0..63
  float* outb = out + (size_t)b * DD * LL + lblk + l0;
#pragma unroll
  for (int dd = 0; dd < 512; dd += 64) {
    const int d = dd + dof;
    float4 r;
    r.x = tile[l0 + 0][d];
    r.y = tile[l0 + 1][d];
    r.z = tile[l0 + 2][d];
    r.w = tile[l0 + 3][d];
    *(float4*)(outb + (size_t)d * LL) = r;
  }
}

extern "C" void kernel_launch(void* const* d_in, const int* in_sizes, int n_in,
                              void* d_out, int out_size, void* d_ws,
                              size_t ws_size, hipStream_t stream) {
  const float* logits = (const float*)d_in[0];
  const float* emb0   = (const float*)d_in[1];
  const float* emb1   = (const float*)d_in[2];
  const float* emb2   = (const float*)d_in[3];
  const float* emb3   = (const float*)d_in[4];
  float*       out    = (float*)d_out;

  float4* part  = (float4*)d_ws;                        // 4 MiB partials
  float4* wpack = (float4*)((char*)d_ws + (size_t)8 * 4 * 4 * LL * 16);

  dim3 ga(8, 4, 32);  // 1024 blocks, 4 waves each -> 16 waves/CU
  topk_part_kernel<<<ga, 256, 0, stream>>>(logits, part);

  topk_merge_kernel<<<256, 256, 0, stream>>>(part, wpack);

  dim3 gb(LL / 16, BB);  // 1024 blocks
  combine_kernel<<<gb, 256, 0, stream>>>(wpack, emb0, emb1, emb2, emb3, out);
}

// Round 4
// 232.054 us; speedup vs baseline: 1.1693x; 1.0091x over previous
//
#include <hip/hip_runtime.h>
#include <math.h>

#define BB 8
#define NN 2048
#define LL 2048
#define QQ 512
#define DD 512

__device__ __forceinline__ void top3_insert(float v, int i, float& m0,
                                            float& m1, float& m2, int& j0,
                                            int& j1, int& j2) {
  bool gt0 = v > m0, gt1 = v > m1, gt2 = v > m2;
  float nv2 = gt1 ? m1 : (gt2 ? v : m2);
  int   ni2 = gt1 ? j1 : (gt2 ? i : j2);
  float nv1 = gt0 ? m0 : (gt1 ? v : m1);
  int   ni1 = gt0 ? j0 : (gt1 ? i : j1);
  m0 = gt0 ? v : m0;
  j0 = gt0 ? i : j0;
  m1 = nv1; j1 = ni1; m2 = nv2; j2 = ni2;
}

// -------- Kernel A: per-wave partial top-3 over a 32-wide n-chunk ---------
// Pure streaming: no LDS, no syncthreads. Grid (8 lt, 4 h, 32 = b*4+ns),
// block 256 = 4 waves; wave g owns chunk ns*4+g (32 n's). Lane u tracks 4
// l's via float4 loads along L; 8-deep explicit load batching. Each thread
// writes 4 partial float4s (64B, coalesced across lanes).
__global__ __launch_bounds__(256) void topk_part_kernel(
    const float* __restrict__ logits, float4* __restrict__ part) {
  const int u     = threadIdx.x & 63;
  const int g     = threadIdx.x >> 6;
  const int lt    = blockIdx.x;       // 0..7
  const int h     = blockIdx.y;       // 0..3
  const int b     = blockIdx.z >> 2;  // 0..7
  const int ns    = blockIdx.z & 3;   // 0..3
  const int chunk = ns * 4 + g;       // 0..15
  const int n0    = chunk * 32;
  const int l4    = lt * 256 + u * 4;

  const float* base = logits + ((size_t)(b * NN + h * QQ + n0) * LL) + l4;

  float v0[4], v1[4], v2[4];
  int   i0[4], i1[4], i2[4];
#pragma unroll
  for (int j = 0; j < 4; ++j) {
    v0[j] = v1[j] = v2[j] = -INFINITY;
    i0[j] = i1[j] = i2[j] = 0;
  }

  float4 buf[8];
  for (int t = 0; t < 4; ++t) {  // 4 batches of 8 n's, 8 loads in flight
#pragma unroll
    for (int p = 0; p < 8; ++p)
      buf[p] = *(const float4*)(base + (size_t)(t * 8 + p) * LL);
#pragma unroll
    for (int p = 0; p < 8; ++p) {
      const int i = n0 + t * 8 + p;
      top3_insert(buf[p].x, i, v0[0], v1[0], v2[0], i0[0], i1[0], i2[0]);
      top3_insert(buf[p].y, i, v0[1], v1[1], v2[1], i0[1], i1[1], i2[1]);
      top3_insert(buf[p].z, i, v0[2], v1[2], v2[2], i0[2], i1[2], i2[2]);
      top3_insert(buf[p].w, i, v0[3], v1[3], v2[3], i0[3], i1[3], i2[3]);
    }
  }

  // part[((b*4+h)*16 + chunk)*LL + l]
  float4* pout = part + ((size_t)((b * 4 + h) * 16 + chunk)) * LL + l4;
#pragma unroll
  for (int j = 0; j < 4; ++j) {
    unsigned int pi = (unsigned int)i0[j] | ((unsigned int)i1[j] << 9) |
                      ((unsigned int)i2[j] << 18);
    pout[j] = make_float4(v0[j], v1[j], v2[j], __uint_as_float(pi));
  }
}

// -------- Kernel B: fused merge + softmax + gather + transpose store ------
// Grid (128 l-tiles, 8 b), block 256 = 4 waves; 16 l x 512 d per block.
// Phase 0: threads 0..63 merge the 16 chunk-partials of one (h,l), softmax,
// stash weights+indices in LDS. Phase 1: wave w handles l's w*4..w*4+3; all
// 64 lanes read the SAME emb row contiguously (float4/lane) -> weighted sum
// -> LDS tile. Phase 2: transposed float4-over-l stores into out(B,d,L).
__global__ __launch_bounds__(256) void combine_kernel(
    const float4* __restrict__ part,
    const float* __restrict__ emb0, const float* __restrict__ emb1,
    const float* __restrict__ emb2, const float* __restrict__ emb3,
    float* __restrict__ out) {
  const int u    = threadIdx.x & 63;
  const int w    = threadIdx.x >> 6;
  const int lblk = blockIdx.x * 16;
  const int b    = blockIdx.y;

  __shared__ float wt_s[4][16][3];
  __shared__ int   rid_s[4][16][3];
  __shared__ float tile[16][516];  // stride 516: 2-way bank alias only (free)

  if (threadIdx.x < 64) {
    const int h  = threadIdx.x >> 4;
    const int il = threadIdx.x & 15;
    const int l  = lblk + il;
    const float4* pp = part + ((size_t)(b * 4 + h) * 16) * LL + l;

    float m0 = -INFINITY, m1 = -INFINITY, m2 = -INFINITY;
    int   j0 = 0, j1 = 0, j2 = 0;
#pragma unroll
    for (int c = 0; c < 16; ++c) {
      float4 P = pp[(size_t)c * LL];
      unsigned int pi = __float_as_uint(P.w);
      top3_insert(P.x, pi & 511, m0, m1, m2, j0, j1, j2);
      top3_insert(P.y, (pi >> 9) & 511, m0, m1, m2, j0, j1, j2);
      top3_insert(P.z, (pi >> 18) & 511, m0, m1, m2, j0, j1, j2);
    }
    float e1 = __expf(m1 - m0), e2 = __expf(m2 - m0);
    float inv = 1.0f / (1.0f + e1 + e2);
    wt_s[h][il][0] = inv;
    wt_s[h][il][1] = e1 * inv;
    wt_s[h][il][2] = e2 * inv;
    rid_s[h][il][0] = j0;
    rid_s[h][il][1] = j1;
    rid_s[h][il][2] = j2;
  }
  __syncthreads();

  const float* embs[4] = {emb0, emb1, emb2, emb3};

#pragma unroll
  for (int il = 0; il < 4; ++il) {
    const int ll = w * 4 + il;
    float wt[12];
    const float* rows[12];
#pragma unroll
    for (int h = 0; h < 4; ++h) {
#pragma unroll
      for (int k = 0; k < 3; ++k) {
        wt[h * 3 + k]   = wt_s[h][ll][k];                       // broadcast
        rows[h * 3 + k] = embs[h] + (size_t)rid_s[h][ll][k] * DD;
      }
    }
#pragma unroll
    for (int p = 0; p < 2; ++p) {
      const int d = p * 256 + u * 4;
      float a0 = 0.f, a1 = 0.f, a2 = 0.f, a3 = 0.f;
#pragma unroll
      for (int m = 0; m < 12; ++m) {
        const float4 e = *(const float4*)(rows[m] + d);  // coalesced 1KB/inst
        a0 += wt[m] * e.x;
        a1 += wt[m] * e.y;
        a2 += wt[m] * e.z;
        a3 += wt[m] * e.w;
      }
      *(float4*)&tile[ll][d] = make_float4(a0, a1, a2, a3);
    }
  }
  __syncthreads();

  const int l0  = (threadIdx.x & 3) * 4;
  const int dof = threadIdx.x >> 2;  // 0..63
  float* outb = out + (size_t)b * DD * LL + lblk + l0;
#pragma unroll
  for (int dd = 0; dd < 512; dd += 64) {
    const int d = dd + dof;
    float4 r;
    r.x = tile[l0 + 0][d];
    r.y = tile[l0 + 1][d];
    r.z = tile[l0 + 2][d];
    r.w = tile[l0 + 3][d];
    *(float4*)(outb + (size_t)d * LL) = r;
  }
}

extern "C" void kernel_launch(void* const* d_in, const int* in_sizes, int n_in,
                              void* d_out, int out_size, void* d_ws,
                              size_t ws_size, hipStream_t stream) {
  const float* logits = (const float*)d_in[0];
  const float* emb0   = (const float*)d_in[1];
  const float* emb1   = (const float*)d_in[2];
  const float* emb2   = (const float*)d_in[3];
  const float* emb3   = (const float*)d_in[4];
  float*       out    = (float*)d_out;
  float4*      part   = (float4*)d_ws;  // 8*4*16*2048 float4 = 16 MiB

  dim3 ga(8, 4, 32);  // 1024 blocks, 16 waves/CU, no LDS
  topk_part_kernel<<<ga, 256, 0, stream>>>(logits, part);

  dim3 gb(LL / 16, BB);  // 1024 blocks
  combine_kernel<<<gb, 256, 0, stream>>>(part, emb0, emb1, emb2, emb3, out);
}